// Round 1
// baseline (1668.715 us; speedup 1.0000x reference)
//
#include <hip/hip_runtime.h>

#define NN 100000   // nodes
#define NE 1600000  // edges
#define FD 128      // IN_DIM (= H*D)
#define CD 112      // CONTENT_DIM
#define PDIM 16     // POS_DIM
#define NH 4        // heads
#define HD 32       // per-head dim
#define HD4 8       // per-head pos dim

__device__ __forceinline__ void atomicMaxFloat(float* addr, float val) {
    // Works for mixed-sign floats with init = -inf:
    // non-negative floats compare correctly as signed ints,
    // negative floats compare inversely as unsigned ints.
    if (val >= 0.0f) atomicMax((int*)addr, __float_as_int(val));
    else             atomicMin((unsigned int*)addr, __float_as_uint(val));
}

// K1: per-node projections + attention scalars + accumulator init.
// One 128-thread block per node.
__global__ __launch_bounds__(128) void node_kernel(
    const float* __restrict__ feat, const float* __restrict__ Wc,
    const float* __restrict__ Wp, const float* __restrict__ attn_src,
    const float* __restrict__ attn_dst, const float* __restrict__ pos_attn_src,
    const float* __restrict__ pos_attn_dst,
    float* __restrict__ hc, float* __restrict__ es, float* __restrict__ ed,
    float* __restrict__ ps, float* __restrict__ pd,
    float* __restrict__ emax, float* __restrict__ esum,
    float* __restrict__ out_acc)
{
    const int n = blockIdx.x;
    const int j = threadIdx.x;  // 0..127 = h*32+d
    __shared__ float f[FD];
    f[j] = feat[n * FD + j];
    __syncthreads();

    // hc[n, j] = dot(content[n,:], Wc[j,:])
    const float* wrow = Wc + j * CD;
    float acc = 0.f;
    #pragma unroll 8
    for (int k = 0; k < CD; ++k) acc = fmaf(f[k], wrow[k], acc);
    hc[n * FD + j] = acc;
    out_acc[n * FD + j] = 0.f;   // zero the ft accumulator (d_out is poisoned)

    // es/ed: reduce acc*attn over d within each 32-lane head group
    float vs = acc * attn_src[j];
    float vd = acc * attn_dst[j];
    #pragma unroll
    for (int off = 16; off > 0; off >>= 1) {
        vs += __shfl_down(vs, off, 32);
        vd += __shfl_down(vd, off, 32);
    }
    if ((j & 31) == 0) {
        es[n * NH + (j >> 5)] = vs;
        ed[n * NH + (j >> 5)] = vd;
    }

    // hp (32 outputs) -> ps/pd, lanes 0..31 only (j = h*8+d4)
    if (j < NH * HD4) {
        const float* prow = Wp + j * PDIM;
        float acp = 0.f;
        #pragma unroll
        for (int k = 0; k < PDIM; ++k) acp = fmaf(f[CD + k], prow[k], acp);
        float vps = acp * pos_attn_src[j];
        float vpd = acp * pos_attn_dst[j];
        #pragma unroll
        for (int off = 4; off > 0; off >>= 1) {
            vps += __shfl_down(vps, off, 8);
            vpd += __shfl_down(vpd, off, 8);
        }
        if ((j & 7) == 0) {
            ps[n * NH + (j >> 3)] = vps;
            pd[n * NH + (j >> 3)] = vpd;
        }
    }
    if (j < NH) {
        emax[n * NH + j] = -__builtin_inff();
        esum[n * NH + j] = 0.f;
    }
}

// K2: per-edge logits + segment max. One thread per (edge, head).
__global__ __launch_bounds__(256) void edge_logits_kernel(
    const int* __restrict__ src, const int* __restrict__ dst,
    const float* __restrict__ es, const float* __restrict__ ed,
    const float* __restrict__ ps, const float* __restrict__ pd,
    const float* __restrict__ att_comb,
    float* __restrict__ e_edge, float* __restrict__ emax)
{
    const int t = blockIdx.x * 256 + threadIdx.x;  // < NE*NH
    const int i = t >> 2;
    const int h = t & 3;
    const int s = src[i];
    const int d = dst[i];
    const float ce = es[s * NH + h] + ed[d * NH + h];
    const float pe = ps[s * NH + h] + pd[d * NH + h];
    float e = ce * att_comb[h * 2 + 0] + pe * att_comb[h * 2 + 1];
    e = e > 0.f ? e : 0.2f * e;  // leaky relu
    e_edge[t] = e;
    atomicMaxFloat(&emax[d * NH + h], e);
}

// K3: fused exp + segment-sum + unnormalized aggregation.
// 128 threads per edge (j = h*32+d); block of 256 covers 2 edges.
__global__ __launch_bounds__(256) void edge_agg_kernel(
    const int* __restrict__ src, const int* __restrict__ dst,
    const float* __restrict__ e_edge, const float* __restrict__ emax,
    const float* __restrict__ hc,
    float* __restrict__ esum, float* __restrict__ out_acc)
{
    const int i = blockIdx.x * 2 + (threadIdx.x >> 7);
    const int j = threadIdx.x & 127;
    const int h = j >> 5;
    const int s = src[i];
    const int d = dst[i];
    const float e = e_edge[i * NH + h];
    const float ex = __expf(e - emax[d * NH + h]);
    if ((j & 31) == 0) atomicAdd(&esum[d * NH + h], ex);
    atomicAdd(&out_acc[d * FD + j], ex * hc[s * FD + j]);
}

// K4: normalize + residual, write diversity loss scalar.
__global__ __launch_bounds__(256) void final_kernel(
    const float* __restrict__ esum, const float* __restrict__ feat,
    float* __restrict__ out)
{
    const int t = blockIdx.x * 256 + threadIdx.x;  // < NN*FD
    const int n = t >> 7;
    const int h = (t >> 5) & 3;
    const float s = esum[n * NH + h];
    const float v = s > 0.f ? out[t] / s : 0.f;
    out[t] = v + feat[t];
    if (t == 0) out[NN * FD] = 0.f;  // diversity_loss
}

extern "C" void kernel_launch(void* const* d_in, const int* in_sizes, int n_in,
                              void* d_out, int out_size, void* d_ws, size_t ws_size,
                              hipStream_t stream) {
    const float* feat         = (const float*)d_in[0];
    const int*   src          = (const int*)d_in[1];
    const int*   dst          = (const int*)d_in[2];
    const float* Wc           = (const float*)d_in[3];
    const float* Wp           = (const float*)d_in[4];
    const float* attn_src     = (const float*)d_in[5];
    const float* attn_dst     = (const float*)d_in[6];
    const float* pos_attn_src = (const float*)d_in[7];
    const float* pos_attn_dst = (const float*)d_in[8];
    const float* att_comb     = (const float*)d_in[9];
    float* out = (float*)d_out;

    // workspace layout (floats): hc | es | ed | ps | pd | emax | esum | e_edge
    float* hc     = (float*)d_ws;                       // NN*FD   = 12.8M
    float* es     = hc   + (size_t)NN * FD;             // NN*NH
    float* ed     = es   + (size_t)NN * NH;
    float* ps     = ed   + (size_t)NN * NH;
    float* pd     = ps   + (size_t)NN * NH;
    float* emax   = pd   + (size_t)NN * NH;
    float* esum   = emax + (size_t)NN * NH;
    float* e_edge = esum + (size_t)NN * NH;             // NE*NH = 6.4M
    // total: 21.6M floats = 86.4 MB

    node_kernel<<<NN, 128, 0, stream>>>(feat, Wc, Wp, attn_src, attn_dst,
                                        pos_attn_src, pos_attn_dst,
                                        hc, es, ed, ps, pd, emax, esum, out);
    edge_logits_kernel<<<(NE * NH) / 256, 256, 0, stream>>>(src, dst, es, ed,
                                                            ps, pd, att_comb,
                                                            e_edge, emax);
    edge_agg_kernel<<<NE / 2, 256, 0, stream>>>(src, dst, e_edge, emax, hc,
                                                esum, out);
    final_kernel<<<(NN * FD) / 256, 256, 0, stream>>>(esum, feat, out);
}

// Round 2
// 544.337 us; speedup vs baseline: 3.0656x; 3.0656x over previous
//
#include <hip/hip_runtime.h>
#include <hip/hip_bf16.h>

#define NN 100000   // nodes
#define NE 1600000  // edges
#define FD 128      // IN_DIM = H*D
#define CD 112      // CONTENT_DIM
#define PDIM 16     // POS_DIM
#define NH 4        // heads
#define NPB 32      // nodes per block (node_kernel)
#define SF 132      // LDS feat row stride (pad 128 -> 132, conflict-free)
#define NB_SCAN 391 // ceil(NN/256)

// ---------------- K1: degree histogram ----------------
__global__ __launch_bounds__(256) void hist_kernel(const int* __restrict__ dst,
                                                   int* __restrict__ deg) {
    const int i = blockIdx.x * 256 + threadIdx.x;  // grid exact: NE/256
    atomicAdd(&deg[dst[i]], 1);
}

// ---------------- K2: node projections ----------------
// hc (bf16), A[n,h] = c0*es + c1*ps, B[n,h] = c0*ed + c1*pd
__global__ __launch_bounds__(256) void node_kernel(
    const float* __restrict__ feat, const float* __restrict__ Wc,
    const float* __restrict__ Wp, const float* __restrict__ attn_src,
    const float* __restrict__ attn_dst, const float* __restrict__ pos_attn_src,
    const float* __restrict__ pos_attn_dst, const float* __restrict__ att_comb,
    __hip_bfloat16* __restrict__ hc_bf, float* __restrict__ A,
    float* __restrict__ B)
{
    const int t = threadIdx.x;
    const int n0 = blockIdx.x * NPB;
    __shared__ float fsh[NPB][SF];
    __shared__ float essh[NPB][NH], edsh[NPB][NH], pssh[NPB][NH], pdsh[NPB][NH];

    // stage feat for 32 nodes (coalesced reads, conflict-free LDS writes)
    #pragma unroll
    for (int r = 0; r < 16; ++r) {
        const int idx = t + r * 256;                 // 0..4095
        fsh[idx >> 7][idx & 127] = feat[(size_t)n0 * FD + idx];
    }
    __syncthreads();

    const int j = t & 127;     // output channel
    const int half = t >> 7;   // which 16-node subset
    // Wc row j in registers (L1/L2-hot across blocks)
    float4 w[28];
    const float4* wrow = (const float4*)(Wc + j * CD);
    #pragma unroll
    for (int q = 0; q < 28; ++q) w[q] = wrow[q];
    const float as_j = attn_src[j], ad_j = attn_dst[j];

    for (int nn = 0; nn < 16; ++nn) {
        const int n = half * 16 + nn;
        float acc = 0.f;
        #pragma unroll
        for (int q = 0; q < 28; ++q) {
            const float4 fv = *(const float4*)&fsh[n][4 * q];  // broadcast
            acc = fmaf(w[q].x, fv.x, acc);
            acc = fmaf(w[q].y, fv.y, acc);
            acc = fmaf(w[q].z, fv.z, acc);
            acc = fmaf(w[q].w, fv.w, acc);
        }
        hc_bf[(size_t)(n0 + n) * FD + j] = __float2bfloat16(acc);
        float vs = acc * as_j, vd = acc * ad_j;
        #pragma unroll
        for (int off = 16; off > 0; off >>= 1) {
            vs += __shfl_down(vs, off, 32);
            vd += __shfl_down(vd, off, 32);
        }
        if ((t & 31) == 0) {
            essh[n][j >> 5] = vs;
            edsh[n][j >> 5] = vd;
        }
    }
    __syncthreads();

    // pos projections: 32 nodes x 32 outputs (o = h*8+d4)
    #pragma unroll
    for (int r = 0; r < 4; ++r) {
        const int idx = t + r * 256;   // 0..1023
        const int n = idx >> 5, o = idx & 31;
        float accp = 0.f;
        const float4* prow = (const float4*)(Wp + o * PDIM);
        #pragma unroll
        for (int q = 0; q < 4; ++q) {
            const float4 pv = prow[q];
            const float4 fv = *(const float4*)&fsh[n][CD + 4 * q];
            accp = fmaf(pv.x, fv.x, accp);
            accp = fmaf(pv.y, fv.y, accp);
            accp = fmaf(pv.z, fv.z, accp);
            accp = fmaf(pv.w, fv.w, accp);
        }
        float vps = accp * pos_attn_src[o], vpd = accp * pos_attn_dst[o];
        #pragma unroll
        for (int off = 4; off > 0; off >>= 1) {
            vps += __shfl_down(vps, off, 8);
            vpd += __shfl_down(vpd, off, 8);
        }
        if ((o & 7) == 0) {
            pssh[n][o >> 3] = vps;
            pdsh[n][o >> 3] = vpd;
        }
    }
    __syncthreads();

    if (t < NPB * NH) {
        const int n = t >> 2, h = t & 3;
        const float c0 = att_comb[h * 2], c1 = att_comb[h * 2 + 1];
        A[(size_t)(n0 + n) * NH + h] = c0 * essh[n][h] + c1 * pssh[n][h];
        B[(size_t)(n0 + n) * NH + h] = c0 * edsh[n][h] + c1 * pdsh[n][h];
    }
}

// ---------------- K3: scan (3 stages) ----------------
__global__ __launch_bounds__(256) void scan1_kernel(const int* __restrict__ deg,
                                                    int* __restrict__ tmp,
                                                    int* __restrict__ bsum) {
    __shared__ int sh[256];
    const int t = threadIdx.x, b = blockIdx.x, i = b * 256 + t;
    const int v = (i < NN) ? deg[i] : 0;
    sh[t] = v;
    __syncthreads();
    #pragma unroll
    for (int off = 1; off < 256; off <<= 1) {
        const int x = (t >= off) ? sh[t - off] : 0;
        __syncthreads();
        sh[t] += x;
        __syncthreads();
    }
    if (i < NN) tmp[i] = sh[t] - v;   // exclusive
    if (t == 255) bsum[b] = sh[t];
}

__global__ void scan2_kernel(int* __restrict__ bsum) {
    if (threadIdx.x == 0) {
        int run = 0;
        for (int b = 0; b < NB_SCAN; ++b) {
            const int v = bsum[b];
            bsum[b] = run;
            run += v;
        }
    }
}

__global__ __launch_bounds__(256) void scan3_kernel(const int* __restrict__ tmp,
                                                    const int* __restrict__ bsum,
                                                    int* __restrict__ row_ptr,
                                                    int* __restrict__ cursor) {
    const int i = blockIdx.x * 256 + threadIdx.x;
    if (i < NN) {
        const int v = tmp[i] + bsum[blockIdx.x];
        row_ptr[i] = v;
        cursor[i] = v;
    }
    if (i == 0) row_ptr[NN] = NE;
}

// ---------------- K4: scatter edges into CSR + logits ----------------
__global__ __launch_bounds__(256) void scatter_kernel(
    const int* __restrict__ src, const int* __restrict__ dst,
    const float* __restrict__ A, const float* __restrict__ B,
    int* __restrict__ cursor, int* __restrict__ col,
    float4* __restrict__ e_csr)
{
    const int i = blockIdx.x * 256 + threadIdx.x;  // grid exact
    const int s = src[i], d = dst[i];
    const int p = atomicAdd(&cursor[d], 1);
    const float4 a = ((const float4*)A)[s];
    const float4 b = ((const float4*)B)[d];
    float4 e;
    e.x = a.x + b.x; e.y = a.y + b.y; e.z = a.z + b.z; e.w = a.w + b.w;
    e.x = e.x > 0.f ? e.x : 0.2f * e.x;
    e.y = e.y > 0.f ? e.y : 0.2f * e.y;
    e.z = e.z > 0.f ? e.z : 0.2f * e.z;
    e.w = e.w > 0.f ? e.w : 0.2f * e.w;
    col[p] = s;
    e_csr[p] = e;
}

// ---------------- K5: per-node fused softmax + aggregate ----------------
// One 64-lane wave per node; lane l owns channels 2l, 2l+1 (head = l>>4).
__global__ __launch_bounds__(256) void agg_kernel(
    const int* __restrict__ row_ptr, const int* __restrict__ col,
    const float* __restrict__ e_csr, const unsigned int* __restrict__ hc_u,
    const float* __restrict__ feat, float* __restrict__ out)
{
    const int n = blockIdx.x * 4 + (threadIdx.x >> 6);
    const int l = threadIdx.x & 63;
    const int r0 = row_ptr[n], r1 = row_ptr[n + 1];

    // phase 1: per-head max (lane handles (edge l>>2, head l&3) strided by 16)
    float m = -3.0e38f;
    for (int p0 = r0; p0 < r1; p0 += 16) {
        const int p = p0 + (l >> 2);
        if (p < r1) m = fmaxf(m, e_csr[p * 4 + (l & 3)]);
    }
    #pragma unroll
    for (int off = 4; off < 64; off <<= 1) m = fmaxf(m, __shfl_xor(m, off));

    // phase 2: per-head sum of exp(e - m)
    float ssum = 0.f;
    for (int p0 = r0; p0 < r1; p0 += 16) {
        const int p = p0 + (l >> 2);
        if (p < r1) ssum += __expf(e_csr[p * 4 + (l & 3)] - m);
    }
    #pragma unroll
    for (int off = 4; off < 64; off <<= 1) ssum += __shfl_xor(ssum, off);

    // lane's own head values (lane h in 0..3 holds head h after butterflies)
    const int hme = l >> 4;
    const float m_mine = __shfl(m, hme);
    const float s_mine = __shfl(ssum, hme);
    const float inv = s_mine > 0.f ? 1.f / s_mine : 0.f;

    // phase 3: weighted gather-accumulate of hc rows (bf16, coalesced 256B)
    float acc0 = 0.f, acc1 = 0.f;
    for (int p = r0; p < r1; ++p) {
        const int c = col[p];                           // broadcast
        const float w = __expf(e_csr[p * 4 + hme] - m_mine);
        const unsigned int u = hc_u[(size_t)c * 64 + l];
        const float f0 = __uint_as_float(u << 16);
        const float f1 = __uint_as_float(u & 0xffff0000u);
        acc0 = fmaf(w, f0, acc0);
        acc1 = fmaf(w, f1, acc1);
    }
    const float2 fv = ((const float2*)(feat + (size_t)n * FD))[l];
    float2 ov;
    ov.x = acc0 * inv + fv.x;
    ov.y = acc1 * inv + fv.y;
    ((float2*)(out + (size_t)n * FD))[l] = ov;
    if (blockIdx.x == 0 && threadIdx.x == 0) out[(size_t)NN * FD] = 0.f;
}

// ---------------- launcher ----------------
extern "C" void kernel_launch(void* const* d_in, const int* in_sizes, int n_in,
                              void* d_out, int out_size, void* d_ws, size_t ws_size,
                              hipStream_t stream) {
    const float* feat         = (const float*)d_in[0];
    const int*   src          = (const int*)d_in[1];
    const int*   dst          = (const int*)d_in[2];
    const float* Wc           = (const float*)d_in[3];
    const float* Wp           = (const float*)d_in[4];
    const float* attn_src     = (const float*)d_in[5];
    const float* attn_dst     = (const float*)d_in[6];
    const float* pos_attn_src = (const float*)d_in[7];
    const float* pos_attn_dst = (const float*)d_in[8];
    const float* att_comb     = (const float*)d_in[9];
    float* out = (float*)d_out;

    // workspace layout (all 16B-aligned)
    char* w = (char*)d_ws;
    __hip_bfloat16* hc_bf = (__hip_bfloat16*)w;        w += (size_t)NN * FD * 2;  // 25.6 MB
    float* A       = (float*)w;                        w += (size_t)NN * NH * 4;  // 1.6 MB
    float* B       = (float*)w;                        w += (size_t)NN * NH * 4;  // 1.6 MB
    int*   deg     = (int*)w;                          w += (size_t)NN * 4;
    int*   tmp     = (int*)w;                          w += (size_t)NN * 4;
    int*   row_ptr = (int*)w;                          w += (size_t)(NN + 4) * 4;
    int*   cursor  = (int*)w;                          w += (size_t)NN * 4;
    int*   bsum    = (int*)w;                          w += 512 * 4;
    int*   col     = (int*)w;                          w += (size_t)NE * 4;       // 6.4 MB
    float* e_csr   = (float*)w;                        /* NE*NH*4 = 25.6 MB */

    hipMemsetAsync(deg, 0, (size_t)NN * sizeof(int), stream);
    hist_kernel<<<NE / 256, 256, 0, stream>>>(dst, deg);
    node_kernel<<<NN / NPB, 256, 0, stream>>>(feat, Wc, Wp, attn_src, attn_dst,
                                              pos_attn_src, pos_attn_dst,
                                              att_comb, hc_bf, A, B);
    scan1_kernel<<<NB_SCAN, 256, 0, stream>>>(deg, tmp, bsum);
    scan2_kernel<<<1, 64, 0, stream>>>(bsum);
    scan3_kernel<<<NB_SCAN, 256, 0, stream>>>(tmp, bsum, row_ptr, cursor);
    scatter_kernel<<<NE / 256, 256, 0, stream>>>(src, dst, A, B, cursor, col,
                                                 (float4*)e_csr);
    agg_kernel<<<NN / 4, 256, 0, stream>>>(row_ptr, col, e_csr,
                                           (const unsigned int*)hc_bf, feat, out);
}

// Round 3
// 502.156 us; speedup vs baseline: 3.3231x; 1.0840x over previous
//
#include <hip/hip_runtime.h>
#include <hip/hip_bf16.h>

#define NN 100000   // nodes
#define NE 1600000  // edges
#define FD 128      // IN_DIM = H*D
#define CD 112      // CONTENT_DIM
#define PDIM 16     // POS_DIM
#define NH 4        // heads
#define NPB 32      // nodes per block (node_kernel)
#define SF 132      // LDS feat row stride (pad 128 -> 132, conflict-free)
#define NB_SCAN 391 // ceil(NN/256)

// ---------------- K1: degree histogram ----------------
__global__ __launch_bounds__(256) void hist_kernel(const int* __restrict__ dst,
                                                   int* __restrict__ deg) {
    const int i = blockIdx.x * 256 + threadIdx.x;  // grid exact: NE/256
    atomicAdd(&deg[dst[i]], 1);
}

// ---------------- K2: node projections ----------------
// hc (bf16), A[n,h] = c0*es + c1*ps, B[n,h] = c0*ed + c1*pd
__global__ __launch_bounds__(256) void node_kernel(
    const float* __restrict__ feat, const float* __restrict__ Wc,
    const float* __restrict__ Wp, const float* __restrict__ attn_src,
    const float* __restrict__ attn_dst, const float* __restrict__ pos_attn_src,
    const float* __restrict__ pos_attn_dst, const float* __restrict__ att_comb,
    __hip_bfloat16* __restrict__ hc_bf, float* __restrict__ A,
    float* __restrict__ B)
{
    const int t = threadIdx.x;
    const int n0 = blockIdx.x * NPB;
    __shared__ float fsh[NPB][SF];
    __shared__ float essh[NPB][NH], edsh[NPB][NH], pssh[NPB][NH], pdsh[NPB][NH];

    // stage feat for 32 nodes (coalesced reads, conflict-free LDS writes)
    #pragma unroll
    for (int r = 0; r < 16; ++r) {
        const int idx = t + r * 256;                 // 0..4095
        fsh[idx >> 7][idx & 127] = feat[(size_t)n0 * FD + idx];
    }
    __syncthreads();

    const int j = t & 127;     // output channel
    const int half = t >> 7;   // which 16-node subset
    // Wc row j in registers (L1/L2-hot across blocks)
    float4 w[28];
    const float4* wrow = (const float4*)(Wc + j * CD);
    #pragma unroll
    for (int q = 0; q < 28; ++q) w[q] = wrow[q];
    const float as_j = attn_src[j], ad_j = attn_dst[j];

    for (int nn = 0; nn < 16; ++nn) {
        const int n = half * 16 + nn;
        float acc = 0.f;
        #pragma unroll
        for (int q = 0; q < 28; ++q) {
            const float4 fv = *(const float4*)&fsh[n][4 * q];  // broadcast
            acc = fmaf(w[q].x, fv.x, acc);
            acc = fmaf(w[q].y, fv.y, acc);
            acc = fmaf(w[q].z, fv.z, acc);
            acc = fmaf(w[q].w, fv.w, acc);
        }
        hc_bf[(size_t)(n0 + n) * FD + j] = __float2bfloat16(acc);
        float vs = acc * as_j, vd = acc * ad_j;
        #pragma unroll
        for (int off = 16; off > 0; off >>= 1) {
            vs += __shfl_down(vs, off, 32);
            vd += __shfl_down(vd, off, 32);
        }
        if ((t & 31) == 0) {
            essh[n][j >> 5] = vs;
            edsh[n][j >> 5] = vd;
        }
    }
    __syncthreads();

    // pos projections: 32 nodes x 32 outputs (o = h*8+d4)
    #pragma unroll
    for (int r = 0; r < 4; ++r) {
        const int idx = t + r * 256;   // 0..1023
        const int n = idx >> 5, o = idx & 31;
        float accp = 0.f;
        const float4* prow = (const float4*)(Wp + o * PDIM);
        #pragma unroll
        for (int q = 0; q < 4; ++q) {
            const float4 pv = prow[q];
            const float4 fv = *(const float4*)&fsh[n][CD + 4 * q];
            accp = fmaf(pv.x, fv.x, accp);
            accp = fmaf(pv.y, fv.y, accp);
            accp = fmaf(pv.z, fv.z, accp);
            accp = fmaf(pv.w, fv.w, accp);
        }
        float vps = accp * pos_attn_src[o], vpd = accp * pos_attn_dst[o];
        #pragma unroll
        for (int off = 4; off > 0; off >>= 1) {
            vps += __shfl_down(vps, off, 8);
            vpd += __shfl_down(vpd, off, 8);
        }
        if ((o & 7) == 0) {
            pssh[n][o >> 3] = vps;
            pdsh[n][o >> 3] = vpd;
        }
    }
    __syncthreads();

    if (t < NPB * NH) {
        const int n = t >> 2, h = t & 3;
        const float c0 = att_comb[h * 2], c1 = att_comb[h * 2 + 1];
        A[(size_t)(n0 + n) * NH + h] = c0 * essh[n][h] + c1 * pssh[n][h];
        B[(size_t)(n0 + n) * NH + h] = c0 * edsh[n][h] + c1 * pdsh[n][h];
    }
}

// ---------------- K3: scan (3 stages) ----------------
__global__ __launch_bounds__(256) void scan1_kernel(const int* __restrict__ deg,
                                                    int* __restrict__ tmp,
                                                    int* __restrict__ bsum) {
    __shared__ int sh[256];
    const int t = threadIdx.x, b = blockIdx.x, i = b * 256 + t;
    const int v = (i < NN) ? deg[i] : 0;
    sh[t] = v;
    __syncthreads();
    #pragma unroll
    for (int off = 1; off < 256; off <<= 1) {
        const int x = (t >= off) ? sh[t - off] : 0;
        __syncthreads();
        sh[t] += x;
        __syncthreads();
    }
    if (i < NN) tmp[i] = sh[t] - v;   // exclusive
    if (t == 255) bsum[b] = sh[t];
}

// parallel block-level exclusive scan over NB_SCAN block sums (<=512)
__global__ __launch_bounds__(512) void scan2_kernel(int* __restrict__ bsum) {
    __shared__ int sh[512];
    const int t = threadIdx.x;
    const int v = (t < NB_SCAN) ? bsum[t] : 0;
    sh[t] = v;
    __syncthreads();
    #pragma unroll
    for (int off = 1; off < 512; off <<= 1) {
        const int x = (t >= off) ? sh[t - off] : 0;
        __syncthreads();
        sh[t] += x;
        __syncthreads();
    }
    if (t < NB_SCAN) bsum[t] = sh[t] - v;   // exclusive
}

__global__ __launch_bounds__(256) void scan3_kernel(const int* __restrict__ tmp,
                                                    const int* __restrict__ bsum,
                                                    int* __restrict__ row_ptr,
                                                    int* __restrict__ cursor) {
    const int i = blockIdx.x * 256 + threadIdx.x;
    if (i < NN) {
        const int v = tmp[i] + bsum[blockIdx.x];
        row_ptr[i] = v;
        cursor[i] = v;
    }
    if (i == 0) row_ptr[NN] = NE;
}

// ---------------- K4: scatter edges into CSR (col only) ----------------
__global__ __launch_bounds__(256) void scatter_kernel(
    const int* __restrict__ src, const int* __restrict__ dst,
    int* __restrict__ cursor, int* __restrict__ col)
{
    const int i = blockIdx.x * 256 + threadIdx.x;  // grid exact
    const int s = src[i], d = dst[i];
    const int p = atomicAdd(&cursor[d], 1);
    col[p] = s;
}

// ---------------- K5: per-node fused softmax + aggregate (single pass) ----
// One 64-lane wave per node; lane l owns channels 2l, 2l+1 (head = l>>4).
// No max subtraction: |e| <~ 3, exp safe in fp32. All 16 lanes of a head
// group compute identical w per edge -> ssum needs no reduction.
__global__ __launch_bounds__(256) void agg_kernel(
    const int* __restrict__ row_ptr, const int* __restrict__ col,
    const float* __restrict__ A, const float* __restrict__ B,
    const unsigned int* __restrict__ hc_u,
    const float* __restrict__ feat, float* __restrict__ out)
{
    const int n = blockIdx.x * 4 + (threadIdx.x >> 6);
    const int l = threadIdx.x & 63;
    const int hme = l >> 4;
    const int r0 = row_ptr[n], r1 = row_ptr[n + 1];

    const float4 bn = ((const float4*)B)[n];
    const float bh = (hme == 0) ? bn.x : (hme == 1) ? bn.y : (hme == 2) ? bn.z
                                                                        : bn.w;
    float ssum = 0.f, acc0 = 0.f, acc1 = 0.f;

    int p = r0;
    for (; p + 4 <= r1; p += 4) {
        // batch the index loads, then issue 4 independent gathers
        const int c0 = col[p], c1 = col[p + 1], c2 = col[p + 2], c3 = col[p + 3];
        const float4 a0 = ((const float4*)A)[c0];
        const float4 a1 = ((const float4*)A)[c1];
        const float4 a2 = ((const float4*)A)[c2];
        const float4 a3 = ((const float4*)A)[c3];
        const unsigned int u0 = hc_u[(size_t)c0 * 64 + l];
        const unsigned int u1 = hc_u[(size_t)c1 * 64 + l];
        const unsigned int u2 = hc_u[(size_t)c2 * 64 + l];
        const unsigned int u3 = hc_u[(size_t)c3 * 64 + l];
        float e0 = ((hme == 0) ? a0.x : (hme == 1) ? a0.y : (hme == 2) ? a0.z : a0.w) + bh;
        float e1 = ((hme == 0) ? a1.x : (hme == 1) ? a1.y : (hme == 2) ? a1.z : a1.w) + bh;
        float e2 = ((hme == 0) ? a2.x : (hme == 1) ? a2.y : (hme == 2) ? a2.z : a2.w) + bh;
        float e3 = ((hme == 0) ? a3.x : (hme == 1) ? a3.y : (hme == 2) ? a3.z : a3.w) + bh;
        e0 = e0 > 0.f ? e0 : 0.2f * e0;
        e1 = e1 > 0.f ? e1 : 0.2f * e1;
        e2 = e2 > 0.f ? e2 : 0.2f * e2;
        e3 = e3 > 0.f ? e3 : 0.2f * e3;
        const float w0 = __expf(e0), w1 = __expf(e1);
        const float w2 = __expf(e2), w3 = __expf(e3);
        ssum += (w0 + w1) + (w2 + w3);
        acc0 = fmaf(w0, __uint_as_float(u0 << 16), acc0);
        acc1 = fmaf(w0, __uint_as_float(u0 & 0xffff0000u), acc1);
        acc0 = fmaf(w1, __uint_as_float(u1 << 16), acc0);
        acc1 = fmaf(w1, __uint_as_float(u1 & 0xffff0000u), acc1);
        acc0 = fmaf(w2, __uint_as_float(u2 << 16), acc0);
        acc1 = fmaf(w2, __uint_as_float(u2 & 0xffff0000u), acc1);
        acc0 = fmaf(w3, __uint_as_float(u3 << 16), acc0);
        acc1 = fmaf(w3, __uint_as_float(u3 & 0xffff0000u), acc1);
    }
    for (; p < r1; ++p) {
        const int c = col[p];
        const float4 a = ((const float4*)A)[c];
        const unsigned int u = hc_u[(size_t)c * 64 + l];
        float e = ((hme == 0) ? a.x : (hme == 1) ? a.y : (hme == 2) ? a.z : a.w) + bh;
        e = e > 0.f ? e : 0.2f * e;
        const float w = __expf(e);
        ssum += w;
        acc0 = fmaf(w, __uint_as_float(u << 16), acc0);
        acc1 = fmaf(w, __uint_as_float(u & 0xffff0000u), acc1);
    }

    const float inv = ssum > 0.f ? 1.f / ssum : 0.f;
    const float2 fv = ((const float2*)(feat + (size_t)n * FD))[l];
    float2 ov;
    ov.x = acc0 * inv + fv.x;
    ov.y = acc1 * inv + fv.y;
    ((float2*)(out + (size_t)n * FD))[l] = ov;
    if (blockIdx.x == 0 && threadIdx.x == 0) out[(size_t)NN * FD] = 0.f;
}

// ---------------- launcher ----------------
extern "C" void kernel_launch(void* const* d_in, const int* in_sizes, int n_in,
                              void* d_out, int out_size, void* d_ws, size_t ws_size,
                              hipStream_t stream) {
    const float* feat         = (const float*)d_in[0];
    const int*   src          = (const int*)d_in[1];
    const int*   dst          = (const int*)d_in[2];
    const float* Wc           = (const float*)d_in[3];
    const float* Wp           = (const float*)d_in[4];
    const float* attn_src     = (const float*)d_in[5];
    const float* attn_dst     = (const float*)d_in[6];
    const float* pos_attn_src = (const float*)d_in[7];
    const float* pos_attn_dst = (const float*)d_in[8];
    const float* att_comb     = (const float*)d_in[9];
    float* out = (float*)d_out;

    // workspace layout (all 16B-aligned)
    char* w = (char*)d_ws;
    __hip_bfloat16* hc_bf = (__hip_bfloat16*)w;        w += (size_t)NN * FD * 2;  // 25.6 MB
    float* A       = (float*)w;                        w += (size_t)NN * NH * 4;  // 1.6 MB
    float* B       = (float*)w;                        w += (size_t)NN * NH * 4;  // 1.6 MB
    int*   deg     = (int*)w;                          w += (size_t)NN * 4;
    int*   tmp     = (int*)w;                          w += (size_t)NN * 4;
    int*   row_ptr = (int*)w;                          w += (size_t)(NN + 4) * 4;
    int*   cursor  = (int*)w;                          w += (size_t)NN * 4;
    int*   bsum    = (int*)w;                          w += 512 * 4;
    int*   col     = (int*)w;                          /* NE*4 = 6.4 MB */

    hipMemsetAsync(deg, 0, (size_t)NN * sizeof(int), stream);
    hist_kernel<<<NE / 256, 256, 0, stream>>>(dst, deg);
    node_kernel<<<NN / NPB, 256, 0, stream>>>(feat, Wc, Wp, attn_src, attn_dst,
                                              pos_attn_src, pos_attn_dst,
                                              att_comb, hc_bf, A, B);
    scan1_kernel<<<NB_SCAN, 256, 0, stream>>>(deg, tmp, bsum);
    scan2_kernel<<<1, 512, 0, stream>>>(bsum);
    scan3_kernel<<<NB_SCAN, 256, 0, stream>>>(tmp, bsum, row_ptr, cursor);
    scatter_kernel<<<NE / 256, 256, 0, stream>>>(src, dst, cursor, col);
    agg_kernel<<<NN / 4, 256, 0, stream>>>(row_ptr, col, A, B,
                                           (const unsigned int*)hc_bf, feat, out);
}

// Round 4
// 458.097 us; speedup vs baseline: 3.6427x; 1.0962x over previous
//
#include <hip/hip_runtime.h>
#include <hip/hip_bf16.h>

#define NN 100000   // nodes
#define NE 1600000  // edges
#define FD 128      // IN_DIM = H*D
#define CD 112      // CONTENT_DIM
#define PDIM 16     // POS_DIM
#define NH 4        // heads
#define NPB 32      // nodes per block (node_kernel)
#define SF 132      // LDS feat row stride (pad 128 -> 132, conflict-free)
#define NB_SCAN 391 // ceil(NN/256)
#define NSHARD 8    // dst shards (one per XCD)
#define SHARD 12500 // NN / NSHARD

// ---------------- K1: degree histogram (XCD-sharded) ----------------
// Block b handles edge chunk b>>3, only edges with dst in shard (b&7).
// Shard counters stay in one XCD's L2 -> no cross-XCD line bouncing.
__global__ __launch_bounds__(256) void hist_kernel(const int* __restrict__ dst,
                                                   int* __restrict__ deg) {
    const int shard = blockIdx.x & (NSHARD - 1);
    const int i = (blockIdx.x >> 3) * 256 + threadIdx.x;  // grid exact
    const int d = dst[i];
    const int lo = shard * SHARD;
    if (d >= lo && d < lo + SHARD) atomicAdd(&deg[d], 1);
}

// ---------------- K2: node projections ----------------
// hc (bf16), A[n,h] = c0*es + c1*ps, B[n,h] = c0*ed + c1*pd
__global__ __launch_bounds__(256) void node_kernel(
    const float* __restrict__ feat, const float* __restrict__ Wc,
    const float* __restrict__ Wp, const float* __restrict__ attn_src,
    const float* __restrict__ attn_dst, const float* __restrict__ pos_attn_src,
    const float* __restrict__ pos_attn_dst, const float* __restrict__ att_comb,
    __hip_bfloat16* __restrict__ hc_bf, float* __restrict__ A,
    float* __restrict__ B)
{
    const int t = threadIdx.x;
    const int n0 = blockIdx.x * NPB;
    __shared__ float fsh[NPB][SF];
    __shared__ float essh[NPB][NH], edsh[NPB][NH], pssh[NPB][NH], pdsh[NPB][NH];

    // stage feat for 32 nodes (coalesced reads, conflict-free LDS writes)
    #pragma unroll
    for (int r = 0; r < 16; ++r) {
        const int idx = t + r * 256;                 // 0..4095
        fsh[idx >> 7][idx & 127] = feat[(size_t)n0 * FD + idx];
    }
    __syncthreads();

    const int j = t & 127;     // output channel
    const int half = t >> 7;   // which 16-node subset
    // Wc row j in registers (L1/L2-hot across blocks)
    float4 w[28];
    const float4* wrow = (const float4*)(Wc + j * CD);
    #pragma unroll
    for (int q = 0; q < 28; ++q) w[q] = wrow[q];
    const float as_j = attn_src[j], ad_j = attn_dst[j];

    for (int nn = 0; nn < 16; ++nn) {
        const int n = half * 16 + nn;
        float acc = 0.f;
        #pragma unroll
        for (int q = 0; q < 28; ++q) {
            const float4 fv = *(const float4*)&fsh[n][4 * q];  // broadcast
            acc = fmaf(w[q].x, fv.x, acc);
            acc = fmaf(w[q].y, fv.y, acc);
            acc = fmaf(w[q].z, fv.z, acc);
            acc = fmaf(w[q].w, fv.w, acc);
        }
        hc_bf[(size_t)(n0 + n) * FD + j] = __float2bfloat16(acc);
        float vs = acc * as_j, vd = acc * ad_j;
        #pragma unroll
        for (int off = 16; off > 0; off >>= 1) {
            vs += __shfl_down(vs, off, 32);
            vd += __shfl_down(vd, off, 32);
        }
        if ((t & 31) == 0) {
            essh[n][j >> 5] = vs;
            edsh[n][j >> 5] = vd;
        }
    }
    __syncthreads();

    // pos projections: 32 nodes x 32 outputs (o = h*8+d4)
    #pragma unroll
    for (int r = 0; r < 4; ++r) {
        const int idx = t + r * 256;   // 0..1023
        const int n = idx >> 5, o = idx & 31;
        float accp = 0.f;
        const float4* prow = (const float4*)(Wp + o * PDIM);
        #pragma unroll
        for (int q = 0; q < 4; ++q) {
            const float4 pv = prow[q];
            const float4 fv = *(const float4*)&fsh[n][CD + 4 * q];
            accp = fmaf(pv.x, fv.x, accp);
            accp = fmaf(pv.y, fv.y, accp);
            accp = fmaf(pv.z, fv.z, accp);
            accp = fmaf(pv.w, fv.w, accp);
        }
        float vps = accp * pos_attn_src[o], vpd = accp * pos_attn_dst[o];
        #pragma unroll
        for (int off = 4; off > 0; off >>= 1) {
            vps += __shfl_down(vps, off, 8);
            vpd += __shfl_down(vpd, off, 8);
        }
        if ((o & 7) == 0) {
            pssh[n][o >> 3] = vps;
            pdsh[n][o >> 3] = vpd;
        }
    }
    __syncthreads();

    if (t < NPB * NH) {
        const int n = t >> 2, h = t & 3;
        const float c0 = att_comb[h * 2], c1 = att_comb[h * 2 + 1];
        A[(size_t)(n0 + n) * NH + h] = c0 * essh[n][h] + c1 * pssh[n][h];
        B[(size_t)(n0 + n) * NH + h] = c0 * edsh[n][h] + c1 * pdsh[n][h];
    }
}

// ---------------- K3: scan (3 stages) ----------------
__global__ __launch_bounds__(256) void scan1_kernel(const int* __restrict__ deg,
                                                    int* __restrict__ tmp,
                                                    int* __restrict__ bsum) {
    __shared__ int sh[256];
    const int t = threadIdx.x, b = blockIdx.x, i = b * 256 + t;
    const int v = (i < NN) ? deg[i] : 0;
    sh[t] = v;
    __syncthreads();
    #pragma unroll
    for (int off = 1; off < 256; off <<= 1) {
        const int x = (t >= off) ? sh[t - off] : 0;
        __syncthreads();
        sh[t] += x;
        __syncthreads();
    }
    if (i < NN) tmp[i] = sh[t] - v;   // exclusive
    if (t == 255) bsum[b] = sh[t];
}

// parallel block-level exclusive scan over NB_SCAN block sums (<=512)
__global__ __launch_bounds__(512) void scan2_kernel(int* __restrict__ bsum) {
    __shared__ int sh[512];
    const int t = threadIdx.x;
    const int v = (t < NB_SCAN) ? bsum[t] : 0;
    sh[t] = v;
    __syncthreads();
    #pragma unroll
    for (int off = 1; off < 512; off <<= 1) {
        const int x = (t >= off) ? sh[t - off] : 0;
        __syncthreads();
        sh[t] += x;
        __syncthreads();
    }
    if (t < NB_SCAN) bsum[t] = sh[t] - v;   // exclusive
}

__global__ __launch_bounds__(256) void scan3_kernel(const int* __restrict__ tmp,
                                                    const int* __restrict__ bsum,
                                                    int* __restrict__ row_ptr,
                                                    int* __restrict__ cursor) {
    const int i = blockIdx.x * 256 + threadIdx.x;
    if (i < NN) {
        const int v = tmp[i] + bsum[blockIdx.x];
        row_ptr[i] = v;
        cursor[i] = v;
    }
    if (i == 0) row_ptr[NN] = NE;
}

// ---------------- K4: scatter edges into CSR (XCD-sharded) ----------------
// Same sharding as hist: cursor range (50 KB) and col range (~800 KB) per
// shard stay in one XCD's L2; col gets written back to HBM once.
__global__ __launch_bounds__(256) void scatter_kernel(
    const int* __restrict__ src, const int* __restrict__ dst,
    int* __restrict__ cursor, int* __restrict__ col)
{
    const int shard = blockIdx.x & (NSHARD - 1);
    const int i = (blockIdx.x >> 3) * 256 + threadIdx.x;  // grid exact
    const int d = dst[i];
    const int s = src[i];          // coalesced; lines fetched anyway
    const int lo = shard * SHARD;
    if (d >= lo && d < lo + SHARD) {
        const int p = atomicAdd(&cursor[d], 1);
        col[p] = s;
    }
}

// ---------------- K5: per-node fused softmax + aggregate (single pass) ----
// One 64-lane wave per node; lane l owns channels 2l, 2l+1 (head = l>>4).
// No max subtraction: |e| <~ 3, exp safe in fp32. All 16 lanes of a head
// group compute identical w per edge -> ssum needs no reduction.
__global__ __launch_bounds__(256) void agg_kernel(
    const int* __restrict__ row_ptr, const int* __restrict__ col,
    const float* __restrict__ A, const float* __restrict__ B,
    const unsigned int* __restrict__ hc_u,
    const float* __restrict__ feat, float* __restrict__ out)
{
    const int n = blockIdx.x * 4 + (threadIdx.x >> 6);
    const int l = threadIdx.x & 63;
    const int hme = l >> 4;
    const int r0 = row_ptr[n], r1 = row_ptr[n + 1];

    const float4 bn = ((const float4*)B)[n];
    const float bh = (hme == 0) ? bn.x : (hme == 1) ? bn.y : (hme == 2) ? bn.z
                                                                        : bn.w;
    float ssum = 0.f, acc0 = 0.f, acc1 = 0.f;

    int p = r0;
    for (; p + 4 <= r1; p += 4) {
        // batch the index loads, then issue 4 independent gathers
        const int c0 = col[p], c1 = col[p + 1], c2 = col[p + 2], c3 = col[p + 3];
        const float4 a0 = ((const float4*)A)[c0];
        const float4 a1 = ((const float4*)A)[c1];
        const float4 a2 = ((const float4*)A)[c2];
        const float4 a3 = ((const float4*)A)[c3];
        const unsigned int u0 = hc_u[(size_t)c0 * 64 + l];
        const unsigned int u1 = hc_u[(size_t)c1 * 64 + l];
        const unsigned int u2 = hc_u[(size_t)c2 * 64 + l];
        const unsigned int u3 = hc_u[(size_t)c3 * 64 + l];
        float e0 = ((hme == 0) ? a0.x : (hme == 1) ? a0.y : (hme == 2) ? a0.z : a0.w) + bh;
        float e1 = ((hme == 0) ? a1.x : (hme == 1) ? a1.y : (hme == 2) ? a1.z : a1.w) + bh;
        float e2 = ((hme == 0) ? a2.x : (hme == 1) ? a2.y : (hme == 2) ? a2.z : a2.w) + bh;
        float e3 = ((hme == 0) ? a3.x : (hme == 1) ? a3.y : (hme == 2) ? a3.z : a3.w) + bh;
        e0 = e0 > 0.f ? e0 : 0.2f * e0;
        e1 = e1 > 0.f ? e1 : 0.2f * e1;
        e2 = e2 > 0.f ? e2 : 0.2f * e2;
        e3 = e3 > 0.f ? e3 : 0.2f * e3;
        const float w0 = __expf(e0), w1 = __expf(e1);
        const float w2 = __expf(e2), w3 = __expf(e3);
        ssum += (w0 + w1) + (w2 + w3);
        acc0 = fmaf(w0, __uint_as_float(u0 << 16), acc0);
        acc1 = fmaf(w0, __uint_as_float(u0 & 0xffff0000u), acc1);
        acc0 = fmaf(w1, __uint_as_float(u1 << 16), acc0);
        acc1 = fmaf(w1, __uint_as_float(u1 & 0xffff0000u), acc1);
        acc0 = fmaf(w2, __uint_as_float(u2 << 16), acc0);
        acc1 = fmaf(w2, __uint_as_float(u2 & 0xffff0000u), acc1);
        acc0 = fmaf(w3, __uint_as_float(u3 << 16), acc0);
        acc1 = fmaf(w3, __uint_as_float(u3 & 0xffff0000u), acc1);
    }
    for (; p < r1; ++p) {
        const int c = col[p];
        const float4 a = ((const float4*)A)[c];
        const unsigned int u = hc_u[(size_t)c * 64 + l];
        float e = ((hme == 0) ? a.x : (hme == 1) ? a.y : (hme == 2) ? a.z : a.w) + bh;
        e = e > 0.f ? e : 0.2f * e;
        const float w = __expf(e);
        ssum += w;
        acc0 = fmaf(w, __uint_as_float(u << 16), acc0);
        acc1 = fmaf(w, __uint_as_float(u & 0xffff0000u), acc1);
    }

    const float inv = ssum > 0.f ? 1.f / ssum : 0.f;
    const float2 fv = ((const float2*)(feat + (size_t)n * FD))[l];
    float2 ov;
    ov.x = acc0 * inv + fv.x;
    ov.y = acc1 * inv + fv.y;
    ((float2*)(out + (size_t)n * FD))[l] = ov;
    if (blockIdx.x == 0 && threadIdx.x == 0) out[(size_t)NN * FD] = 0.f;
}

// ---------------- launcher ----------------
extern "C" void kernel_launch(void* const* d_in, const int* in_sizes, int n_in,
                              void* d_out, int out_size, void* d_ws, size_t ws_size,
                              hipStream_t stream) {
    const float* feat         = (const float*)d_in[0];
    const int*   src          = (const int*)d_in[1];
    const int*   dst          = (const int*)d_in[2];
    const float* Wc           = (const float*)d_in[3];
    const float* Wp           = (const float*)d_in[4];
    const float* attn_src     = (const float*)d_in[5];
    const float* attn_dst     = (const float*)d_in[6];
    const float* pos_attn_src = (const float*)d_in[7];
    const float* pos_attn_dst = (const float*)d_in[8];
    const float* att_comb     = (const float*)d_in[9];
    float* out = (float*)d_out;

    // workspace layout (all 16B-aligned)
    char* w = (char*)d_ws;
    __hip_bfloat16* hc_bf = (__hip_bfloat16*)w;        w += (size_t)NN * FD * 2;  // 25.6 MB
    float* A       = (float*)w;                        w += (size_t)NN * NH * 4;  // 1.6 MB
    float* B       = (float*)w;                        w += (size_t)NN * NH * 4;  // 1.6 MB
    int*   deg     = (int*)w;                          w += (size_t)NN * 4;
    int*   tmp     = (int*)w;                          w += (size_t)NN * 4;
    int*   row_ptr = (int*)w;                          w += (size_t)(NN + 4) * 4;
    int*   cursor  = (int*)w;                          w += (size_t)NN * 4;
    int*   bsum    = (int*)w;                          w += 512 * 4;
    int*   col     = (int*)w;                          /* NE*4 = 6.4 MB */

    hipMemsetAsync(deg, 0, (size_t)NN * sizeof(int), stream);
    hist_kernel<<<NSHARD * (NE / 256), 256, 0, stream>>>(dst, deg);
    node_kernel<<<NN / NPB, 256, 0, stream>>>(feat, Wc, Wp, attn_src, attn_dst,
                                              pos_attn_src, pos_attn_dst,
                                              att_comb, hc_bf, A, B);
    scan1_kernel<<<NB_SCAN, 256, 0, stream>>>(deg, tmp, bsum);
    scan2_kernel<<<1, 512, 0, stream>>>(bsum);
    scan3_kernel<<<NB_SCAN, 256, 0, stream>>>(tmp, bsum, row_ptr, cursor);
    scatter_kernel<<<NSHARD * (NE / 256), 256, 0, stream>>>(src, dst, cursor, col);
    agg_kernel<<<NN / 4, 256, 0, stream>>>(row_ptr, col, A, B,
                                           (const unsigned int*)hc_bf, feat, out);
}